// Round 13
// baseline (284.947 us; speedup 1.0000x reference)
//
#include <hip/hip_runtime.h>
#include <hip/hip_bf16.h>

#define DEVI __device__ __forceinline__

typedef __attribute__((ext_vector_type(8))) __bf16 bf16x8;
typedef __attribute__((ext_vector_type(4))) float f32x4;
typedef __attribute__((ext_vector_type(8))) unsigned short u16x8;
typedef unsigned short u16;

typedef unsigned int __attribute__((address_space(1))) gu32;
typedef unsigned int __attribute__((address_space(3))) lu32;

DEVI u16 f2bf(float f) {
  unsigned u = __builtin_bit_cast(unsigned, f);
  u += 0x7fffu + ((u >> 16) & 1u);
  return (u16)(u >> 16);
}
DEVI float bf2f(u16 h) {
  unsigned u = ((unsigned)h) << 16;
  return __builtin_bit_cast(float, u);
}

// async global->LDS, 16B per lane. LDS dest must be linear in lane order.
DEVI void async_copy16(const void* g, void* l) {
  __builtin_amdgcn_global_load_lds((gu32*)(unsigned long long)g, (lu32*)l, 16, 0, 0);
}

// ---------------- prep: LN1 + all weight packing in ONE launch ----------------
// blocks 0..2047: LN1 (4 rows each, fp32 -> bf16)
// 2048+: pack blocks: 0..191 Wq/Wk/Wv  192..255 Wp
//        256..511 W1 (scaled by g2 -> W1gT; k-block-0 also computes Bv/G1)
//        512..767 W2   768: bias concat + zero stats
__global__ __launch_bounds__(256) void prep_kernel(
    const float* __restrict__ x, const float* __restrict__ g1,
    const float* __restrict__ be1, u16* __restrict__ h_bf,
    const float* __restrict__ Wq, const float* __restrict__ Wk,
    const float* __restrict__ Wv, const float* __restrict__ Wp,
    const float* __restrict__ W1, const float* __restrict__ W2,
    u16* __restrict__ WqT, u16* __restrict__ WpT,
    u16* __restrict__ W1gT, u16* __restrict__ W2T,
    const float* __restrict__ bq, const float* __restrict__ bk,
    const float* __restrict__ bv, float* __restrict__ bqkv,
    const float* __restrict__ g2, const float* __restrict__ be2,
    float* __restrict__ Bv, float* __restrict__ G1, float* __restrict__ stats)
{
  __shared__ u16 tile[64 * 65];
  __shared__ float redB[4][64], redG[4][64];
  int bid = blockIdx.x;
  if (bid < 2048) {   // ---- LN1, one wave per row ----
    int w = threadIdx.x >> 6, l = threadIdx.x & 63;
    int row = bid * 4 + w;
    const float4* xr = (const float4*)(x + (size_t)row * 512);
    float4 a = xr[l * 2], b = xr[l * 2 + 1];
    float e[8] = {a.x, a.y, a.z, a.w, b.x, b.y, b.z, b.w};
    float s = 0.f;
#pragma unroll
    for (int j = 0; j < 8; ++j) s += e[j];
#pragma unroll
    for (int m = 1; m < 64; m <<= 1) s += __shfl_xor(s, m);
    float mean = s * (1.0f / 512.0f);
    float vs = 0.f;
#pragma unroll
    for (int j = 0; j < 8; ++j) { float d = e[j] - mean; vs += d * d; }
#pragma unroll
    for (int m = 1; m < 64; m <<= 1) vs += __shfl_xor(vs, m);
    float rstd = rsqrtf(vs * (1.0f / 512.0f) + 1e-5f);
    const float4* gp = (const float4*)g1;
    const float4* bp = (const float4*)be1;
    float4 g0 = gp[l * 2], g1v = gp[l * 2 + 1];
    float4 e0 = bp[l * 2], e1v = bp[l * 2 + 1];
    float gg[8] = {g0.x, g0.y, g0.z, g0.w, g1v.x, g1v.y, g1v.z, g1v.w};
    float bb[8] = {e0.x, e0.y, e0.z, e0.w, e1v.x, e1v.y, e1v.z, e1v.w};
    u16x8 o;
#pragma unroll
    for (int j = 0; j < 8; ++j) o[j] = f2bf((e[j] - mean) * rstd * gg[j] + bb[j]);
    *(u16x8*)(h_bf + (size_t)row * 512 + l * 8) = o;
    return;
  }
  int pbid = bid - 2048;
  if (pbid == 768) {   // bias concat + zero LN2-stats buffer
    for (int j = 0; j < 6; ++j) {
      int i = j * 256 + threadIdx.x;
      float v = (i < 512) ? bq[i] : (i < 1024 ? bk[i - 512] : bv[i - 1024]);
      bqkv[i] = v;
    }
    float4 z = {0.f, 0.f, 0.f, 0.f};
    for (int j = threadIdx.x; j < 4096; j += 256) ((float4*)stats)[j] = z;
    return;
  }
  const float* W; u16* dst; int K, N, nx, rel; bool isW1 = false;
  if (pbid < 192) {
    int m = pbid >> 6; rel = pbid & 63;
    W = m == 0 ? Wq : (m == 1 ? Wk : Wv);
    dst = WqT + (size_t)m * 512 * 512; K = 512; N = 512; nx = 8;
  } else if (pbid < 256) {
    rel = pbid - 192; W = Wp; dst = WpT; K = 512; N = 512; nx = 8;
  } else if (pbid < 512) {
    rel = pbid - 256; W = W1; dst = W1gT; K = 512; N = 2048; nx = 32; isW1 = true;
  } else {
    rel = pbid - 512; W = W2; dst = W2T; K = 2048; N = 512; nx = 8;
  }
  int n0 = (rel % nx) * 64, k0 = (rel / nx) * 64;
  int tx = threadIdx.x & 63, ty = threadIdx.x >> 6;
#pragma unroll
  for (int i = 0; i < 16; ++i) {
    int r = i * 4 + ty;
    float sc = isW1 ? g2[k0 + r] : 1.0f;
    tile[tx * 65 + r] = f2bf(W[(size_t)(k0 + r) * N + n0 + tx] * sc);
  }
  __syncthreads();
#pragma unroll
  for (int i = 0; i < 16; ++i) {
    int nl = i * 4 + ty;
    dst[(size_t)(n0 + nl) * K + k0 + tx] = tile[nl * 65 + tx];
  }
  // LN2-fusion vectors: k-block-0 W1 blocks compute full-K column sums
  if (isW1 && k0 == 0) {
    float sB = 0.f, sG = 0.f;
    for (int k = ty; k < 512; k += 4) {
      float wv = W1[(size_t)k * 2048 + n0 + tx];
      sB += be2[k] * wv; sG += g2[k] * wv;
    }
    redB[ty][tx] = sB; redG[ty][tx] = sG;
    __syncthreads();
    if (ty == 0) {
      Bv[n0 + tx] = redB[0][tx] + redB[1][tx] + redB[2][tx] + redB[3][tx];
      G1[n0 + tx] = redG[0][tx] + redG[1][tx] + redG[2][tx] + redG[3][tx];
    }
  }
}

// ---------------- GEMM: C[M][N] = A[M][K](bf16) * BT[N][K](bf16) + bias ----------------
// EPI 0: bf16 out
// EPI 3: proj: bf16(v + fp32 res) + per-row LN2 stats atomics
// EPI 4: fp32 out + bf16 res
// EPI 5: MLP1: LN2 affine (rstd*acc - mu*rstd*G1 + Bv + b1) + exact-erf GELU -> bf16
template <int EPI, int BN>
__global__ __launch_bounds__(256) void gemm_bt(
    const u16* __restrict__ A, const u16* __restrict__ BT,
    const float* __restrict__ bias, const void* __restrict__ res,
    void* __restrict__ out, int M, int N, int K,
    const float* __restrict__ Bv, const float* __restrict__ G1,
    float* __restrict__ stats)
{
  constexpr int MI = (BN == 128) ? 4 : 2;     // M-frags per wave
  constexpr int WROWS = MI * 16;
  __shared__ __align__(16) u16 Asm[128 * 64];
  __shared__ __align__(16) u16 Bsm[BN * 64];
  int tid = threadIdx.x;
  int l = tid & 63, w = tid >> 6;
  int wm = (BN == 128) ? (w >> 1) : w;
  int wn = (BN == 128) ? (w & 1) : 0;
  size_t bm = (size_t)blockIdx.x * 128, bn = (size_t)blockIdx.y * BN;
  int lr = l & 15, lh = l >> 4;
  f32x4 acc[MI][4];
#pragma unroll
  for (int mi = 0; mi < MI; ++mi)
#pragma unroll
    for (int ni = 0; ni < 4; ++ni) acc[mi][ni] = (f32x4){0.f, 0.f, 0.f, 0.f};
  int srow = tid >> 3, sseg = tid & 7;

  for (int k0 = 0; k0 < K; k0 += 64) {
    __syncthreads();
#pragma unroll
    for (int i = 0; i < 4; ++i) {
      int r = i * 32 + srow;
      int gcol = k0 + ((sseg ^ (r & 7)) << 3);   // pre-swizzled source, linear LDS dest
      async_copy16(A + (bm + r) * (size_t)K + gcol, &Asm[r * 64 + sseg * 8]);
    }
#pragma unroll
    for (int i = 0; i < BN / 32; ++i) {
      int r = i * 32 + srow;
      int gcol = k0 + ((sseg ^ (r & 7)) << 3);
      async_copy16(BT + (bn + r) * (size_t)K + gcol, &Bsm[r * 64 + sseg * 8]);
    }
    __syncthreads();
#pragma unroll
    for (int kk = 0; kk < 2; ++kk) {
      bf16x8 af[MI], bfr[4];
#pragma unroll
      for (int mi = 0; mi < MI; ++mi) {
        int r = wm * WROWS + mi * 16 + lr;
        int sl = kk * 4 + lh;
        af[mi] = *(const bf16x8*)&Asm[r * 64 + ((sl ^ (r & 7)) << 3)];
      }
#pragma unroll
      for (int ni = 0; ni < 4; ++ni) {
        int r = wn * 64 + ni * 16 + lr;
        int sl = kk * 4 + lh;
        bfr[ni] = *(const bf16x8*)&Bsm[r * 64 + ((sl ^ (r & 7)) << 3)];
      }
#pragma unroll
      for (int mi = 0; mi < MI; ++mi)
#pragma unroll
        for (int ni = 0; ni < 4; ++ni)
          acc[mi][ni] = __builtin_amdgcn_mfma_f32_16x16x32_bf16(af[mi], bfr[ni], acc[mi][ni], 0, 0, 0);
    }
  }
  // epilogue: C layout col=lane&15, row=(lane>>4)*4+reg
  float rs[MI][4], rq[MI][4];       // EPI3 per-row partials
  float rstd_[MI][4], mrs_[MI][4];  // EPI5 per-row LN2 factors
  if constexpr (EPI == 3) {
#pragma unroll
    for (int mi = 0; mi < MI; ++mi)
#pragma unroll
      for (int r = 0; r < 4; ++r) { rs[mi][r] = 0.f; rq[mi][r] = 0.f; }
  }
  if constexpr (EPI == 5) {
#pragma unroll
    for (int mi = 0; mi < MI; ++mi)
#pragma unroll
      for (int r = 0; r < 4; ++r) {
        size_t row = bm + wm * WROWS + mi * 16 + lh * 4 + r;
        float s = stats[row * 2], q = stats[row * 2 + 1];
        float mu = s * (1.0f / 512.0f);
        float var = q * (1.0f / 512.0f) - mu * mu;
        float rst = rsqrtf(var + 1e-5f);
        rstd_[mi][r] = rst; mrs_[mi][r] = mu * rst;
      }
  }
#pragma unroll
  for (int ni = 0; ni < 4; ++ni) {
    size_t col = bn + wn * 64 + ni * 16 + lr;
    float bvcol = bias[col];
    float bvv = 0.f, g1v = 0.f;
    if constexpr (EPI == 5) { bvv = Bv[col] + bvcol; g1v = G1[col]; }
#pragma unroll
    for (int mi = 0; mi < MI; ++mi) {
      size_t row0 = bm + wm * WROWS + mi * 16 + lh * 4;
#pragma unroll
      for (int r = 0; r < 4; ++r) {
        size_t idx = (row0 + r) * (size_t)N + col;
        if constexpr (EPI == 3) {
          float x1v = acc[mi][ni][r] + bvcol + ((const float*)res)[idx];
          ((u16*)out)[idx] = f2bf(x1v);
          rs[mi][r] += x1v; rq[mi][r] += x1v * x1v;
        } else if constexpr (EPI == 4) {
          ((float*)out)[idx] = acc[mi][ni][r] + bvcol + bf2f(((const u16*)res)[idx]);
        } else if constexpr (EPI == 5) {
          float v = acc[mi][ni][r] * rstd_[mi][r] + bvv - mrs_[mi][r] * g1v;
          float t = 0.5f * v * (1.0f + erff(v * 0.70710678118654752f));
          ((u16*)out)[idx] = f2bf(t);
        } else {
          ((u16*)out)[idx] = f2bf(acc[mi][ni][r] + bvcol);
        }
      }
    }
  }
  if constexpr (EPI == 3) {   // LN2 row-stats: reduce over 16 col-lanes, one atomic per row
#pragma unroll
    for (int mi = 0; mi < MI; ++mi)
#pragma unroll
      for (int r = 0; r < 4; ++r) {
        float s_ = rs[mi][r], q_ = rq[mi][r];
        s_ += __shfl_xor(s_, 1); q_ += __shfl_xor(q_, 1);
        s_ += __shfl_xor(s_, 2); q_ += __shfl_xor(q_, 2);
        s_ += __shfl_xor(s_, 4); q_ += __shfl_xor(q_, 4);
        s_ += __shfl_xor(s_, 8); q_ += __shfl_xor(q_, 8);
        if (lr == 0) {
          size_t row = bm + wm * WROWS + mi * 16 + lh * 4 + r;
          atomicAdd(&stats[row * 2], s_);
          atomicAdd(&stats[row * 2 + 1], q_);
        }
      }
  }
}

// ---------------- flash attention, causal, d=64, H=8, T=2048 ----------------
// r4 structure (measured 63.5-64.4 us): paired 64-row Q tiles {bx, 31-bx},
// dbuf K (global_load_lds) + V (reg-staged, swizzled V^T), 2 barriers/tile,
// next-tile staging issued after fragment reads. No-max exp2 softmax.
__global__ __launch_bounds__(256) void attn_kernel(
    const u16* __restrict__ QKV, u16* __restrict__ Y)
{
  constexpr int T = 2048, CS = 1536;
  __shared__ __align__(16) u16 Ksm[2][64 * 64];
  __shared__ __align__(16) u16 Vsm[2][64 * 64];  // V^T, XOR-swizzled
  __shared__ __align__(16) u16 Psm[4][16 * 64];
  int tid = threadIdx.x;
  int l = tid & 63, w = tid >> 6;
  int lr = l & 15, lh = l >> 4;
  int bh = blockIdx.y;
  int b = bh >> 3, h = bh & 7;
  size_t rowbase = ((size_t)b * T) * CS + h * 64;
  const u16* Qp = QKV + rowbase;
  const u16* Kp = QKV + rowbase + 512;
  const u16* Vp = QKV + rowbase + 1024;
  int srow = tid >> 3, sseg = tid & 7;
  int tv = tid >> 2, c0 = (tid & 3) * 16;
  u16* P = &Psm[w][0];
  const float qscale = 0.125f * 1.44269504088896340736f;  // 1/sqrt(d) * log2(e)

  for (int pass = 0; pass < 2; ++pass) {
    int qt = pass ? (31 - (int)blockIdx.x) : (int)blockIdx.x;
    int qw = qt * 64 + w * 16;   // wave's 16 q-rows

    bf16x8 qfr[2];
#pragma unroll
    for (int ks = 0; ks < 2; ++ks) {
      u16x8 raw = *(const u16x8*)(Qp + (size_t)(qw + lr) * CS + ks * 32 + lh * 8);
#pragma unroll
      for (int j = 0; j < 8; ++j) raw[j] = f2bf(bf2f(raw[j]) * qscale);
      qfr[ks] = __builtin_bit_cast(bf16x8, raw);
    }

    float lsum[4];
    f32x4 accO[4];
#pragma unroll
    for (int r = 0; r < 4; ++r) lsum[r] = 0.f;
#pragma unroll
    for (int df = 0; df < 4; ++df) accO[df] = (f32x4){0.f, 0.f, 0.f, 0.f};

    int nt = qt + 1;
    // prologue: stage tile 0
#pragma unroll
    for (int i = 0; i < 2; ++i) {
      int r = i * 32 + srow;
      int gcol = (sseg ^ (r & 7)) << 3;
      async_copy16(Kp + (size_t)r * CS + gcol, &Ksm[0][r * 64 + sseg * 8]);
    }
    const u16* vp0 = Vp + (size_t)tv * CS + c0;
    u16x8 v0 = *(const u16x8*)vp0;
    u16x8 v1 = *(const u16x8*)(vp0 + 8);

    int cur = 0;
    for (int it = 0; it < nt; ++it) {
      int t0 = it * 64;
      __syncthreads();   // Ksm[cur] staged (vmcnt drained pre-barrier); bufs free
      // V^T swizzled store into Vsm[cur]
#pragma unroll
      for (int j = 0; j < 8; ++j) {
        int d0 = c0 + j, d1 = c0 + 8 + j;
        Vsm[cur][d0 * 64 + (tv ^ (((d0 >> 3) & 7) << 3))] = v0[j];
        Vsm[cur][d1 * 64 + (tv ^ (((d1 >> 3) & 7) << 3))] = v1[j];
      }
      bf16x8 kfr[4][2];
#pragma unroll
      for (int tf = 0; tf < 4; ++tf)
#pragma unroll
        for (int ks = 0; ks < 2; ++ks) {
          int r = tf * 16 + lr, sl = ks * 4 + lh;
          kfr[tf][ks] = *(const bf16x8*)&Ksm[cur][r * 64 + ((sl ^ (r & 7)) << 3)];
        }
      __syncthreads();   // Vsm[cur] visible
      bf16x8 vfr[4][2];
#pragma unroll
      for (int tf = 0; tf < 4; ++tf)
#pragma unroll
        for (int ks = 0; ks < 2; ++ks) {
          int d = tf * 16 + lr;
          vfr[tf][ks] = *(const bf16x8*)&Vsm[cur][d * 64 + ((ks * 32 + lh * 8) ^ (((d >> 3) & 7) << 3))];
        }
      // issue next tile's staging now -> overlaps with compute below
      if (it + 1 < nt) {
        int t1 = t0 + 64;
#pragma unroll
        for (int i = 0; i < 2; ++i) {
          int r = i * 32 + srow;
          int gcol = (sseg ^ (r & 7)) << 3;
          async_copy16(Kp + (size_t)(t1 + r) * CS + gcol, &Ksm[cur ^ 1][r * 64 + sseg * 8]);
        }
        const u16* vp = Vp + (size_t)(t1 + tv) * CS + c0;
        v0 = *(const u16x8*)vp;
        v1 = *(const u16x8*)(vp + 8);
      }

      f32x4 s[4];
      __builtin_amdgcn_s_setprio(1);
#pragma unroll
      for (int tf = 0; tf < 4; ++tf) {
        s[tf] = (f32x4){0.f, 0.f, 0.f, 0.f};
#pragma unroll
        for (int ks = 0; ks < 2; ++ks)
          s[tf] = __builtin_amdgcn_mfma_f32_16x16x32_bf16(qfr[ks], kfr[tf][ks], s[tf], 0, 0, 0);
      }
      __builtin_amdgcn_s_setprio(0);

      if (t0 + 63 > qw) {   // causal mask (diagonal tile only)
#pragma unroll
        for (int tf = 0; tf < 4; ++tf) {
          int t = t0 + tf * 16 + lr;
#pragma unroll
          for (int r = 0; r < 4; ++r) {
            int qr = qw + lh * 4 + r;
            if (t > qr) s[tf][r] = -1e30f;
          }
        }
      }
      // no-max softmax: exp2 directly, per-lane partial sums, pack to P
#pragma unroll
      for (int tf = 0; tf < 4; ++tf)
#pragma unroll
        for (int r = 0; r < 4; ++r) {
          float p = exp2f(s[tf][r]);
          s[tf][r] = p;
          lsum[r] += p;
        }
#pragma unroll
      for (int tf = 0; tf < 4; ++tf)
#pragma unroll
        for (int r = 0; r < 4; ++r) {
          int qq = lh * 4 + r, t = tf * 16 + lr;
          P[qq * 64 + (((t >> 3) ^ (qq & 7)) << 3) + (t & 7)] = f2bf(s[tf][r]);
        }
      bf16x8 pa[2];
#pragma unroll
      for (int ks = 0; ks < 2; ++ks) {
        int sl = ks * 4 + lh;
        pa[ks] = *(const bf16x8*)&P[lr * 64 + ((sl ^ (lr & 7)) << 3)];
      }
      __builtin_amdgcn_s_setprio(1);
#pragma unroll
      for (int df = 0; df < 4; ++df)
#pragma unroll
        for (int ks = 0; ks < 2; ++ks)
          accO[df] = __builtin_amdgcn_mfma_f32_16x16x32_bf16(pa[ks], vfr[df][ks], accO[df], 0, 0, 0);
      __builtin_amdgcn_s_setprio(0);
      cur ^= 1;
    }
    // epilogue: reduce per-lane partial sums over the 16-lane row group
    size_t ybase = ((size_t)b * T) * 512 + h * 64;
#pragma unroll
    for (int r = 0; r < 4; ++r) {
      float ls = lsum[r];
      ls += __shfl_xor(ls, 1); ls += __shfl_xor(ls, 2);
      ls += __shfl_xor(ls, 4); ls += __shfl_xor(ls, 8);
      float inv = 1.0f / ls;
      size_t qg = qw + lh * 4 + r;
#pragma unroll
      for (int df = 0; df < 4; ++df)
        Y[ybase + qg * 512 + df * 16 + lr] = f2bf(accO[df][r] * inv);
    }
  }
}

// ---------------- launch ----------------
extern "C" void kernel_launch(void* const* d_in, const int* in_sizes, int n_in,
                              void* d_out, int out_size, void* d_ws, size_t ws_size,
                              hipStream_t stream)
{
  const int B = 4, T = 2048, C = 512;
  const int M = B * T;  // 8192
  const float* x   = (const float*)d_in[0];
  const float* g1  = (const float*)d_in[1];
  const float* be1 = (const float*)d_in[2];
  const float* g2  = (const float*)d_in[3];
  const float* be2 = (const float*)d_in[4];
  const float* Wq  = (const float*)d_in[5];  const float* bq = (const float*)d_in[6];
  const float* Wk  = (const float*)d_in[7];  const float* bk = (const float*)d_in[8];
  const float* Wv  = (const float*)d_in[9];  const float* bv = (const float*)d_in[10];
  const float* Wp  = (const float*)d_in[11]; const float* bp = (const float*)d_in[12];
  const float* W1  = (const float*)d_in[13]; const float* b1 = (const float*)d_in[14];
  const float* W2  = (const float*)d_in[15]; const float* b2 = (const float*)d_in[16];
  float* out = (float*)d_out;

  char* ws = (char*)d_ws;
  u16* h_bf   = (u16*)(ws);                          // 8MB [8192][512]
  u16* qkv_bf = (u16*)(ws + (8ull << 20));           // 24MB [8192][1536]
  u16* act    = (u16*)(ws);                          // 32MB [8192][2048], aliases h+qkv (both dead)
  u16* y_bf   = (u16*)(ws + (32ull << 20));          // 8MB [8192][512]
  u16* x1_bf  = (u16*)(ws + (40ull << 20));          // 8MB bf16 residual stream
  u16* WqT    = (u16*)(ws + (64ull << 20));          // [512][512] x3 contiguous -> [1536][512]
  u16* WkT    = WqT + 512 * 512;
  u16* WvT    = WkT + 512 * 512;
  u16* WpT    = WvT + 512 * 512;
  u16* W1gT   = WpT + 512 * 512;                     // [2048][512], g2-scaled
  u16* W2T    = W1gT + 2048 * 512;                   // [512][2048]
  float* bqkv = (float*)(ws + (72ull << 20));        // [1536]
  float* stats = (float*)(ws + (73ull << 20));       // [8192][2] LN2 row stats
  float* Bv   = stats + 8192 * 2;                    // [2048]
  float* G1   = Bv + 2048;                           // [2048]

  // LN1 + all weight prep in one launch (pack blocks offset by 2048)
  prep_kernel<<<2817, 256, 0, stream>>>(x, g1, be1, h_bf,
                                        Wq, Wk, Wv, Wp, W1, W2,
                                        WqT, WpT, W1gT, W2T,
                                        bq, bk, bv, bqkv, g2, be2,
                                        Bv, G1, stats);

  // fused QKV: [8192][512] x [1536][512]^T -> [8192][1536]
  gemm_bt<0, 128><<<dim3(64, 12), 256, 0, stream>>>(h_bf, WqT, bqkv, nullptr, qkv_bf,
                                                    M, 1536, 512, nullptr, nullptr, nullptr);
  // attention (r4 structure)
  attn_kernel<<<dim3(16, 32), 256, 0, stream>>>(qkv_bf, y_bf);
  // proj + bias + fp32 residual(x) -> x1 bf16, plus LN2 row-stats atomics
  gemm_bt<3, 64><<<dim3(64, 8), 256, 0, stream>>>(y_bf, WpT, bp, x, x1_bf,
                                                  M, 512, 512, nullptr, nullptr, stats);
  // MLP1 with fused LN2 affine + GELU: x1_bf @ W1g^T -> act
  gemm_bt<5, 128><<<dim3(64, 16), 256, 0, stream>>>(x1_bf, W1gT, b1, nullptr, act,
                                                    M, 2048, 512, Bv, G1, stats);
  // MLP2 + bias + bf16 residual(x1) -> out fp32
  gemm_bt<4, 64><<<dim3(64, 8), 256, 0, stream>>>(act, W2T, b2, x1_bf, out,
                                                  M, 512, 2048, nullptr, nullptr, nullptr);
}